// Round 13
// baseline (247.822 us; speedup 1.0000x reference)
//
#include <hip/hip_runtime.h>

// types
typedef __attribute__((ext_vector_type(8))) short bf16x8;
typedef __attribute__((ext_vector_type(4))) short bf16x4;
typedef __attribute__((ext_vector_type(4))) float f32x4;

#define DEVI static __device__ __forceinline__

DEVI unsigned short f2b(float f) {
  union { float f; unsigned u; } v; v.f = f;
  unsigned r = v.u + 0x7fffu + ((v.u >> 16) & 1u);
  return (unsigned short)(r >> 16);
}
DEVI unsigned pk2(float lo, float hi) {
  return (unsigned)f2b(lo) | ((unsigned)f2b(hi) << 16);
}

typedef const __attribute__((address_space(1))) void* gas1_t;
typedef __attribute__((address_space(3))) void* las3_t;
#define GL16(g, l) __builtin_amdgcn_global_load_lds((gas1_t)(g), (las3_t)(l), 16, 0, 0)
#define LDSOFF(p) ((unsigned)(size_t)(__attribute__((address_space(3))) void*)(p))

#define WAITVM(N) asm volatile("s_waitcnt vmcnt(" #N ")" ::: "memory")
#define WAITLGKM  asm volatile("s_waitcnt lgkmcnt(0)" ::: "memory")
#define SCHEDBAR  __builtin_amdgcn_sched_barrier(0)

// ---- workspace layout (bytes) ----
#define OFF_WQKV  0ull          // 768*512*2
#define OFF_WR    786432ull     // 512*256*2
#define OFF_BQKV  1048576ull
#define OFF_SCALE 1051648ull
#define OFF_OFF2  1053696ull
#define OFF_Y     35651584ull   // y bf16 [16][256][4096] = 32 MiB
#define OFF_Q     69206016ull   // qkv bf16: q,k,v each 16777216 u16

// ---------------- P0: weight prep ----------------
__global__ __launch_bounds__(256) void k_prep(
    const float* __restrict__ Wq, const float* __restrict__ bq,
    const float* __restrict__ Wk, const float* __restrict__ bk,
    const float* __restrict__ Wv, const float* __restrict__ bv,
    const float* __restrict__ Wr, const float* __restrict__ br,
    const float* __restrict__ gamma, const float* __restrict__ beta,
    const float* __restrict__ rm, const float* __restrict__ rv,
    unsigned short* __restrict__ wqkv, unsigned short* __restrict__ wrb,
    float* __restrict__ bqkv, float* __restrict__ scale, float* __restrict__ off2)
{
  int i = blockIdx.x * 256 + threadIdx.x;
  if (i < 768 * 512) {
    int o = i >> 9, c = i & 511;
    float v = (o < 256) ? Wq[o * 512 + c] : (o < 512 ? Wk[(o - 256) * 512 + c] : Wv[(o - 512) * 512 + c]);
    wqkv[i] = f2b(v);
  }
  if (i < 512 * 256) wrb[i] = f2b(Wr[i]);
  if (i < 768) bqkv[i] = (i < 256) ? bq[i] : (i < 512 ? bk[i - 256] : bv[i - 512]);
  if (i < 512) {
    float inv = gamma[i] * rsqrtf(rv[i] + 1e-5f);
    scale[i] = inv;
    off2[i] = (br[i] - rm[i]) * inv + beta[i];
  }
}

// ---------------- G1: QKV GEMM reading x DIRECTLY (f32), transpose+convert in staging ----------------
// 128x128 tile, BK=64. A (wqkv) via GL16 + XOR swizzle (round-12 proven). B-tile [64 c][128 s] from
// x[b][c][s]: reg-stage 8x float4 per thread, f2b-convert, write subtiled LDS [c/4][s/16][4][16],
// B-fragments via ds_read_b64_tr_b16 (round-12-proven machinery, identical geometry to recon's).
__global__ __launch_bounds__(256) void k_qkv(
    const float* __restrict__ x, const unsigned short* __restrict__ wqkv,
    const float* __restrict__ bqkv, unsigned short* __restrict__ qkv)
{
  __shared__ unsigned short Albuf[2][8192];   // A: [128 o][64 c], XOR-swizzled, 16 KB each
  __shared__ unsigned short Blbuf[2][8192];   // B: [16 c4][8 sg][4][16], 16 KB each
  const int b = blockIdx.z, o0 = blockIdx.y * 128, s0 = blockIdx.x * 128;
  const int t = threadIdx.x, w = t >> 6, l = t & 63;
  const int wm = w >> 1, wn = w & 1, lr = l & 15, g = l >> 4;
  const int lkE = g * 8;
  const int swE = (lr & 7) * 8;
  const int cp = (t & 7) ^ ((t >> 3) & 7);

  const unsigned short* Ag = wqkv + (size_t)(o0 + (t >> 3)) * 512 + cp * 8;
  // B: thread stages row c = kt*64 + (t>>2), s-chunk s0 + (t&3)*32 (32 f32 = 8 float4)
  const float* Bg = x + ((size_t)b * 512 + (t >> 2)) * 4096 + s0 + (t & 3) * 32;
  const int bwbase = (t >> 4) * 1024 + (t & 3) * 256 + ((t >> 2) & 3) * 32;  // bytes
  const int trbase = g * 2048 + wn * 512 + lr * 8;                            // bytes

  const f32x4 z = {0.f, 0.f, 0.f, 0.f};
  f32x4 acc[4][4];
  #pragma unroll
  for (int i = 0; i < 4; ++i)
    #pragma unroll
    for (int j = 0; j < 4; ++j) acc[i][j] = z;

  float4 fr0, fr1, fr2, fr3, fr4, fr5, fr6, fr7;

#define ASTG(st, kt) do { \
    _Pragma("unroll") \
    for (int j = 0; j < 4; ++j) \
      GL16(Ag + (kt) * 64 + j * 32 * 512, (char*)&Albuf[st][0] + j * 4096 + t * 16); \
  } while (0)

#define BLOAD(kt) do { \
    const float* bp_ = Bg + (size_t)(kt) * 64 * 4096; \
    fr0 = *(const float4*)(bp_ + 0);  fr1 = *(const float4*)(bp_ + 4); \
    fr2 = *(const float4*)(bp_ + 8);  fr3 = *(const float4*)(bp_ + 12); \
    fr4 = *(const float4*)(bp_ + 16); fr5 = *(const float4*)(bp_ + 20); \
    fr6 = *(const float4*)(bp_ + 24); fr7 = *(const float4*)(bp_ + 28); \
  } while (0)

#define BWRITE(st) do { \
    char* bp_ = (char*)&Blbuf[st][0] + bwbase; \
    uint4 c0_ = { pk2(fr0.x, fr0.y), pk2(fr0.z, fr0.w), pk2(fr1.x, fr1.y), pk2(fr1.z, fr1.w) }; \
    uint4 c1_ = { pk2(fr2.x, fr2.y), pk2(fr2.z, fr2.w), pk2(fr3.x, fr3.y), pk2(fr3.z, fr3.w) }; \
    uint4 c2_ = { pk2(fr4.x, fr4.y), pk2(fr4.z, fr4.w), pk2(fr5.x, fr5.y), pk2(fr5.z, fr5.w) }; \
    uint4 c3_ = { pk2(fr6.x, fr6.y), pk2(fr6.z, fr6.w), pk2(fr7.x, fr7.y), pk2(fr7.z, fr7.w) }; \
    *(uint4*)(bp_ + 0)   = c0_; \
    *(uint4*)(bp_ + 16)  = c1_; \
    *(uint4*)(bp_ + 128) = c2_; \
    *(uint4*)(bp_ + 144) = c3_; \
  } while (0)

#define TR2(dst, k0, k1) do { \
    bf16x4 t0_, t1_; \
    asm volatile("ds_read_b64_tr_b16 %0, %1 offset:" #k0 : "=v"(t0_) : "v"(ta)); \
    asm volatile("ds_read_b64_tr_b16 %0, %1 offset:" #k1 : "=v"(t1_) : "v"(ta)); \
    (dst) = __builtin_shufflevector(t0_, t1_, 0, 1, 2, 3, 4, 5, 6, 7); \
  } while (0)

#define CMP_Q(st) do { \
    const unsigned short* A = &Albuf[st][0]; \
    unsigned ta = LDSOFF(&Blbuf[st][0]) + (unsigned)trbase; \
    bf16x8 af[2][4], bfr[2][4]; \
    _Pragma("unroll") \
    for (int kc = 0; kc < 2; ++kc) { \
      const int kidx = (kc * 32 + lkE) ^ swE; \
      _Pragma("unroll") \
      for (int mi = 0; mi < 4; ++mi) af[kc][mi] = *(const bf16x8*)(A + (wm * 64 + mi * 16 + lr) * 64 + kidx); \
    } \
    TR2(bfr[0][0], 0, 1024);    TR2(bfr[0][1], 128, 1152); \
    TR2(bfr[0][2], 256, 1280);  TR2(bfr[0][3], 384, 1408); \
    TR2(bfr[1][0], 8192, 9216); TR2(bfr[1][1], 8320, 9344); \
    TR2(bfr[1][2], 8448, 9472); TR2(bfr[1][3], 8576, 9600); \
    WAITLGKM; SCHEDBAR; \
    _Pragma("unroll") \
    for (int kc = 0; kc < 2; ++kc) \
      _Pragma("unroll") \
      for (int mi = 0; mi < 4; ++mi) \
        _Pragma("unroll") \
        for (int ni = 0; ni < 4; ++ni) \
          acc[mi][ni] = __builtin_amdgcn_mfma_f32_16x16x32_bf16(af[kc][mi], bfr[kc][ni], acc[mi][ni], 0, 0, 0); \
  } while (0)

  // prologue (vmcnt invariant: at each WAITVM(4), only the newest ASTG may remain)
  ASTG(0, 0); BLOAD(0); ASTG(1, 1);
  WAITVM(4);                      // A0,B0 done
  BWRITE(0); BLOAD(1);
  WAITLGKM;
  __builtin_amdgcn_s_barrier(); SCHEDBAR;
  #pragma unroll
  for (int kt = 0; kt < 6; ++kt) {
    CMP_Q(kt & 1);
    __builtin_amdgcn_s_barrier(); SCHEDBAR;
    ASTG(kt & 1, kt + 2);
    WAITVM(4);                    // A(kt+1),B(kt+1) done; A(kt+2) in flight
    BWRITE((kt + 1) & 1);
    BLOAD(kt + 2);
    WAITLGKM;
    __builtin_amdgcn_s_barrier(); SCHEDBAR;
  }
  CMP_Q(0);                       // kt=6
  __builtin_amdgcn_s_barrier(); SCHEDBAR;
  WAITVM(0);                      // A7,B7 done
  BWRITE(1);
  WAITLGKM;
  __builtin_amdgcn_s_barrier(); SCHEDBAR;
  CMP_Q(1);                       // kt=7

  // epilogue: D row = o, col = s; store bf16 to q/k/v
  #pragma unroll
  for (int mi = 0; mi < 4; ++mi) {
    #pragma unroll
    for (int reg = 0; reg < 4; ++reg) {
      const int o = o0 + wm * 64 + mi * 16 + (l >> 4) * 4 + reg;
      const float bias = bqkv[o];
      const size_t base = (size_t)(o >> 8) * 16777216ull + ((size_t)b * 256 + (o & 255)) * 4096;
      #pragma unroll
      for (int ni = 0; ni < 4; ++ni) {
        const int s = s0 + wn * 64 + ni * 16 + lr;
        qkv[base + s] = f2b(acc[mi][ni][reg] + bias);
      }
    }
  }
#undef ASTG
#undef BLOAD
#undef BWRITE
#undef TR2
#undef CMP_Q
}

// ---------------- G2: per-group attention ----------------
__global__ __launch_bounds__(256) void k_attn(const unsigned short* __restrict__ qkv,
                                              unsigned short* __restrict__ yout)
{
  __shared__ unsigned short Vt[64][80];
  __shared__ unsigned short P[4][16][80];
  const int g = blockIdx.x;
  const unsigned short* qg = qkv + (size_t)g * 4096;
  const unsigned short* kg = qkv + 16777216ull + (size_t)g * 4096;
  const unsigned short* vg = qkv + 33554432ull + (size_t)g * 4096;
  const int t = threadIdx.x, w = t >> 6, l = t & 63;
  const int lr = l & 15, lk = (l >> 4) * 8;

  {
    const int j = t >> 2, c0 = (t & 3) * 16;
    bf16x8 a = *(const bf16x8*)(vg + j * 64 + c0);
    bf16x8 bb = *(const bf16x8*)(vg + j * 64 + c0 + 8);
    #pragma unroll
    for (int jj = 0; jj < 8; ++jj) { Vt[c0 + jj][j] = a[jj]; Vt[c0 + 8 + jj][j] = bb[jj]; }
  }

  const f32x4 z = {0.f, 0.f, 0.f, 0.f};
  bf16x8 qf[2];
  #pragma unroll
  for (int kc = 0; kc < 2; ++kc) qf[kc] = *(const bf16x8*)(qg + (w * 16 + lr) * 64 + kc * 32 + lk);
  f32x4 accS[4] = {z, z, z, z};
  __builtin_amdgcn_s_setprio(1);
  #pragma unroll
  for (int jt = 0; jt < 4; ++jt)
    #pragma unroll
    for (int kc = 0; kc < 2; ++kc) {
      bf16x8 kf = *(const bf16x8*)(kg + (jt * 16 + lr) * 64 + kc * 32 + lk);
      accS[jt] = __builtin_amdgcn_mfma_f32_16x16x32_bf16(qf[kc], kf, accS[jt], 0, 0, 0);
    }
  __builtin_amdgcn_s_setprio(0);

  #pragma unroll
  for (int reg = 0; reg < 4; ++reg) {
    float mx = fmaxf(fmaxf(accS[0][reg], accS[1][reg]), fmaxf(accS[2][reg], accS[3][reg]));
    #pragma unroll
    for (int m = 1; m < 16; m <<= 1) mx = fmaxf(mx, __shfl_xor(mx, m, 64));
    float e0 = __expf(accS[0][reg] - mx), e1 = __expf(accS[1][reg] - mx);
    float e2 = __expf(accS[2][reg] - mx), e3 = __expf(accS[3][reg] - mx);
    float sm = e0 + e1 + e2 + e3;
    #pragma unroll
    for (int m = 1; m < 16; m <<= 1) sm += __shfl_xor(sm, m, 64);
    const float rs = 1.f / sm;
    const int row = (l >> 4) * 4 + reg;
    P[w][row][0 * 16 + lr] = f2b(e0 * rs);
    P[w][row][1 * 16 + lr] = f2b(e1 * rs);
    P[w][row][2 * 16 + lr] = f2b(e2 * rs);
    P[w][row][3 * 16 + lr] = f2b(e3 * rs);
  }
  __syncthreads();

  bf16x8 pf[2];
  #pragma unroll
  for (int kc = 0; kc < 2; ++kc) pf[kc] = *(const bf16x8*)(&P[w][lr][kc * 32 + lk]);
  f32x4 accY[4] = {z, z, z, z};
  __builtin_amdgcn_s_setprio(1);
  #pragma unroll
  for (int nt = 0; nt < 4; ++nt)
    #pragma unroll
    for (int kc = 0; kc < 2; ++kc) {
      bf16x8 vf = *(const bf16x8*)(&Vt[nt * 16 + lr][kc * 32 + lk]);
      accY[nt] = __builtin_amdgcn_mfma_f32_16x16x32_bf16(pf[kc], vf, accY[nt], 0, 0, 0);
    }
  __builtin_amdgcn_s_setprio(0);

  unsigned short* yg = yout + (size_t)g * 4096;
  #pragma unroll
  for (int nt = 0; nt < 4; ++nt)
    #pragma unroll
    for (int reg = 0; reg < 4; ++reg) {
      const int i = w * 16 + (l >> 4) * 4 + reg;
      yg[i * 64 + nt * 16 + lr] = f2b(accY[nt][reg]);
    }
}

// ---------------- G3: recon GEMM + BN + residual; reads y via ds_read_b64_tr_b16 (round-12 proven) ----------------
__global__ __launch_bounds__(256) void k_recon(
    const unsigned short* __restrict__ y, const unsigned short* __restrict__ wrb,
    const float* __restrict__ scale, const float* __restrict__ off2,
    const float* __restrict__ x, float* __restrict__ out)
{
  __shared__ unsigned short Albuf[2][8192];   // A: [128 o][64 cr], XOR-swizzled
  __shared__ unsigned short Blbuf[2][8192];   // B: [16 cr4][8 sg][4][16]
  const int b = blockIdx.z, o0 = blockIdx.y * 128, s0 = blockIdx.x * 128;
  const int t = threadIdx.x, w = t >> 6, l = t & 63;
  const int wm = w >> 1, wn = w & 1, lr = l & 15, g = l >> 4;
  const int lkE = g * 8;
  const int swE = (lr & 7) * 8;
  const int cp = (t & 7) ^ ((t >> 3) & 7);

  const unsigned short* Ag = wrb + (size_t)(o0 + (t >> 3)) * 256 + cp * 8;
  const unsigned short* Bg = y + ((size_t)b * 256 + (t >> 2)) * 4096 + s0 + (t & 3) * 32;
  const int bwbase = (t >> 4) * 1024 + (t & 3) * 256 + ((t >> 2) & 3) * 32;
  const int trbase = g * 2048 + wn * 512 + lr * 8;

  const f32x4 z = {0.f, 0.f, 0.f, 0.f};
  f32x4 acc[4][4];
  #pragma unroll
  for (int i = 0; i < 4; ++i)
    #pragma unroll
    for (int j = 0; j < 4; ++j) acc[i][j] = z;

  uint4 br0, br1, br2, br3;

#define ASTG(st, kt) do { \
    _Pragma("unroll") \
    for (int j = 0; j < 4; ++j) \
      GL16(Ag + (kt) * 64 + j * 32 * 256, (char*)&Albuf[st][0] + j * 4096 + t * 16); \
  } while (0)

#define BLOAD(kt) do { \
    br0 = *(const uint4*)(Bg + (size_t)(kt) * 64 * 4096 + 0); \
    br1 = *(const uint4*)(Bg + (size_t)(kt) * 64 * 4096 + 8); \
    br2 = *(const uint4*)(Bg + (size_t)(kt) * 64 * 4096 + 16); \
    br3 = *(const uint4*)(Bg + (size_t)(kt) * 64 * 4096 + 24); \
  } while (0)

#define BWRITE(st) do { \
    char* bp_ = (char*)&Blbuf[st][0] + bwbase; \
    *(uint4*)(bp_ + 0)   = br0; \
    *(uint4*)(bp_ + 16)  = br1; \
    *(uint4*)(bp_ + 128) = br2; \
    *(uint4*)(bp_ + 144) = br3; \
  } while (0)

#define TR2(dst, k0, k1) do { \
    bf16x4 t0_, t1_; \
    asm volatile("ds_read_b64_tr_b16 %0, %1 offset:" #k0 : "=v"(t0_) : "v"(ta)); \
    asm volatile("ds_read_b64_tr_b16 %0, %1 offset:" #k1 : "=v"(t1_) : "v"(ta)); \
    (dst) = __builtin_shufflevector(t0_, t1_, 0, 1, 2, 3, 4, 5, 6, 7); \
  } while (0)

#define CMP_R(st) do { \
    const unsigned short* A = &Albuf[st][0]; \
    unsigned ta = LDSOFF(&Blbuf[st][0]) + (unsigned)trbase; \
    bf16x8 af[2][4], bfr[2][4]; \
    _Pragma("unroll") \
    for (int kc = 0; kc < 2; ++kc) { \
      const int kidx = (kc * 32 + lkE) ^ swE; \
      _Pragma("unroll") \
      for (int mi = 0; mi < 4; ++mi) af[kc][mi] = *(const bf16x8*)(A + (wm * 64 + mi * 16 + lr) * 64 + kidx); \
    } \
    TR2(bfr[0][0], 0, 1024);    TR2(bfr[0][1], 128, 1152); \
    TR2(bfr[0][2], 256, 1280);  TR2(bfr[0][3], 384, 1408); \
    TR2(bfr[1][0], 8192, 9216); TR2(bfr[1][1], 8320, 9344); \
    TR2(bfr[1][2], 8448, 9472); TR2(bfr[1][3], 8576, 9600); \
    WAITLGKM; SCHEDBAR; \
    _Pragma("unroll") \
    for (int kc = 0; kc < 2; ++kc) \
      _Pragma("unroll") \
      for (int mi = 0; mi < 4; ++mi) \
        _Pragma("unroll") \
        for (int ni = 0; ni < 4; ++ni) \
          acc[mi][ni] = __builtin_amdgcn_mfma_f32_16x16x32_bf16(af[kc][mi], bfr[kc][ni], acc[mi][ni], 0, 0, 0); \
  } while (0)

  // prologue
  ASTG(0, 0); BLOAD(0); ASTG(1, 1);
  WAITVM(4);
  BWRITE(0); BLOAD(1);
  WAITLGKM;
  __builtin_amdgcn_s_barrier(); SCHEDBAR;
  CMP_R(0);
  __builtin_amdgcn_s_barrier(); SCHEDBAR;
  ASTG(0, 2);
  WAITVM(4);
  BWRITE(1); BLOAD(2);
  WAITLGKM;
  __builtin_amdgcn_s_barrier(); SCHEDBAR;
  CMP_R(1);
  __builtin_amdgcn_s_barrier(); SCHEDBAR;
  ASTG(1, 3);
  WAITVM(4);
  BWRITE(0); BLOAD(3);
  WAITLGKM;
  __builtin_amdgcn_s_barrier(); SCHEDBAR;
  CMP_R(0);
  __builtin_amdgcn_s_barrier(); SCHEDBAR;
  WAITVM(0);
  BWRITE(1);
  WAITLGKM;
  __builtin_amdgcn_s_barrier(); SCHEDBAR;
  CMP_R(1);

  // ---- epilogue with one-chunk-ahead x prefetch ----
  const int lrow = (l >> 4) * 4;
  float xr0[16], xr1[16];

#define XLOAD(dstarr, mi) do { \
    _Pragma("unroll") \
    for (int reg = 0; reg < 4; ++reg) { \
      const int o_ = o0 + wm * 64 + (mi) * 16 + lrow + reg; \
      const size_t base_ = ((size_t)b * 512 + o_) * 4096; \
      _Pragma("unroll") \
      for (int ni = 0; ni < 4; ++ni) \
        dstarr[reg * 4 + ni] = x[base_ + s0 + wn * 64 + ni * 16 + lr]; \
    } \
  } while (0)

#define XSTORE(srcarr, mi) do { \
    _Pragma("unroll") \
    for (int reg = 0; reg < 4; ++reg) { \
      const int o_ = o0 + wm * 64 + (mi) * 16 + lrow + reg; \
      const float sc_ = scale[o_], of_ = off2[o_]; \
      const size_t base_ = ((size_t)b * 512 + o_) * 4096; \
      _Pragma("unroll") \
      for (int ni = 0; ni < 4; ++ni) { \
        const size_t idx_ = base_ + s0 + wn * 64 + ni * 16 + lr; \
        out[idx_] = acc[mi][ni][reg] * sc_ + of_ + srcarr[reg * 4 + ni]; \
      } \
    } \
  } while (0)

  XLOAD(xr0, 0);
  XLOAD(xr1, 1); SCHEDBAR;
  XSTORE(xr0, 0);
  XLOAD(xr0, 2); SCHEDBAR;
  XSTORE(xr1, 1);
  XLOAD(xr1, 3); SCHEDBAR;
  XSTORE(xr0, 2);
  XSTORE(xr1, 3);
#undef XLOAD
#undef XSTORE
#undef ASTG
#undef BLOAD
#undef BWRITE
#undef TR2
#undef CMP_R
}

extern "C" void kernel_launch(void* const* d_in, const int* in_sizes, int n_in,
                              void* d_out, int out_size, void* d_ws, size_t ws_size,
                              hipStream_t stream)
{
  const float* x     = (const float*)d_in[0];
  const float* Wq    = (const float*)d_in[1];
  const float* bq    = (const float*)d_in[2];
  const float* Wk    = (const float*)d_in[3];
  const float* bk    = (const float*)d_in[4];
  const float* Wv    = (const float*)d_in[5];
  const float* bv    = (const float*)d_in[6];
  const float* Wr    = (const float*)d_in[7];
  const float* br    = (const float*)d_in[8];
  const float* gamma = (const float*)d_in[9];
  const float* beta  = (const float*)d_in[10];
  const float* rm    = (const float*)d_in[11];
  const float* rv    = (const float*)d_in[12];

  char* ws = (char*)d_ws;
  unsigned short* wqkv  = (unsigned short*)(ws + OFF_WQKV);
  unsigned short* wrb   = (unsigned short*)(ws + OFF_WR);
  float* bqkv  = (float*)(ws + OFF_BQKV);
  float* scale = (float*)(ws + OFF_SCALE);
  float* off2  = (float*)(ws + OFF_OFF2);
  unsigned short* yb  = (unsigned short*)(ws + OFF_Y);
  unsigned short* qkv = (unsigned short*)(ws + OFF_Q);
  float* out = (float*)d_out;

  hipLaunchKernelGGL(k_prep, dim3(1536), dim3(256), 0, stream,
                     Wq, bq, Wk, bk, Wv, bv, Wr, br, gamma, beta, rm, rv,
                     wqkv, wrb, bqkv, scale, off2);
  hipLaunchKernelGGL(k_qkv, dim3(32, 6, 16), dim3(256), 0, stream, x, wqkv, bqkv, qkv);
  hipLaunchKernelGGL(k_attn, dim3(4096), dim3(256), 0, stream, qkv, yb);
  hipLaunchKernelGGL(k_recon, dim3(32, 4, 16), dim3(256), 0, stream, yb, wrb, scale, off2, x, out);
}

// Round 14
// 195.356 us; speedup vs baseline: 1.2686x; 1.2686x over previous
//
#include <hip/hip_runtime.h>

// types
typedef __attribute__((ext_vector_type(8))) short bf16x8;
typedef __attribute__((ext_vector_type(4))) short bf16x4;
typedef __attribute__((ext_vector_type(4))) float f32x4;

#define DEVI static __device__ __forceinline__

DEVI unsigned short f2b(float f) {
  union { float f; unsigned u; } v; v.f = f;
  unsigned r = v.u + 0x7fffu + ((v.u >> 16) & 1u);
  return (unsigned short)(r >> 16);
}

typedef const __attribute__((address_space(1))) void* gas1_t;
typedef __attribute__((address_space(3))) void* las3_t;
#define GL16(g, l) __builtin_amdgcn_global_load_lds((gas1_t)(g), (las3_t)(l), 16, 0, 0)
#define LDSOFF(p) ((unsigned)(size_t)(__attribute__((address_space(3))) void*)(p))

#define WAITVM(N) asm volatile("s_waitcnt vmcnt(" #N ")" ::: "memory")
#define WAITLGKM  asm volatile("s_waitcnt lgkmcnt(0)" ::: "memory")
#define SCHEDBAR  __builtin_amdgcn_sched_barrier(0)

// ---- workspace layout (bytes) ----
#define OFF_WQKV  0ull          // 768*512*2
#define OFF_WR    786432ull     // 512*256*2
#define OFF_BQKV  1048576ull
#define OFF_SCALE 1051648ull
#define OFF_OFF2  1053696ull
#define OFF_XT    2097152ull    // xt bf16 [16][4096][512] = 64 MiB (dead after qkv)
#define OFF_Y     35651584ull   // y  bf16 [16][256][4096] = 32 MiB (aliases xt tail; attn after qkv)
#define OFF_Q     69206016ull   // qkv bf16: q,k,v each 16777216 u16

// ---------------- P1: x [B][C][S] f32 -> xt [B][S][C] bf16  (+ fused weight prep) ----------------
__global__ __launch_bounds__(256) void k_xt(
    const float* __restrict__ x, unsigned short* __restrict__ xt,
    const float* __restrict__ Wq, const float* __restrict__ bq,
    const float* __restrict__ Wk, const float* __restrict__ bk,
    const float* __restrict__ Wv, const float* __restrict__ bv,
    const float* __restrict__ Wr, const float* __restrict__ br,
    const float* __restrict__ gamma, const float* __restrict__ beta,
    const float* __restrict__ rm, const float* __restrict__ rv,
    unsigned short* __restrict__ wqkv, unsigned short* __restrict__ wrb,
    float* __restrict__ bqkv, float* __restrict__ scale, float* __restrict__ off2)
{
  __shared__ unsigned short tile[64][72];
  const int t = threadIdx.x;
  const int bid = blockIdx.x + blockIdx.y * 64 + blockIdx.z * 512;

  if (bid < 1536) {
    int i = bid * 256 + t;
    if (i < 768 * 512) {
      int o = i >> 9, c = i & 511;
      float v = (o < 256) ? Wq[o * 512 + c] : (o < 512 ? Wk[(o - 256) * 512 + c] : Wv[(o - 512) * 512 + c]);
      wqkv[i] = f2b(v);
    }
    if (i < 512 * 256) wrb[i] = f2b(Wr[i]);
    if (i < 768) bqkv[i] = (i < 256) ? bq[i] : (i < 512 ? bk[i - 256] : bv[i - 512]);
    if (i < 512) {
      float inv = gamma[i] * rsqrtf(rv[i] + 1e-5f);
      scale[i] = inv;
      off2[i] = (br[i] - rm[i]) * inv + beta[i];
    }
  }

  const int b = blockIdx.z, c0 = blockIdx.y * 64, s0 = blockIdx.x * 64;
  const int r = t >> 2, cc = (t & 3) * 16;
  const float* src = x + ((size_t)b * 512 + c0 + r) * 4096 + s0 + cc;
  #pragma unroll
  for (int j = 0; j < 16; j += 4) {
    float4 v = *(const float4*)(src + j);
    tile[r][cc + j + 0] = f2b(v.x);
    tile[r][cc + j + 1] = f2b(v.y);
    tile[r][cc + j + 2] = f2b(v.z);
    tile[r][cc + j + 3] = f2b(v.w);
  }
  __syncthreads();
  unsigned short* dst = xt + ((size_t)b * 4096 + s0 + r) * 512 + c0 + cc;
  bf16x8 o0, o1;
  #pragma unroll
  for (int j = 0; j < 8; ++j) { o0[j] = tile[cc + j][r]; o1[j] = tile[cc + 8 + j][r]; }
  *(bf16x8*)(dst) = o0;
  *(bf16x8*)(dst + 8) = o1;
}

// ---------------- G1: QKV GEMM, 128x128, BK=64, ring-2, swizzled LDS, loads-upfront CMP ----------------
__global__ __launch_bounds__(256) void k_qkv(
    const unsigned short* __restrict__ xt, const unsigned short* __restrict__ wqkv,
    const float* __restrict__ bqkv, unsigned short* __restrict__ qkv)
{
  __shared__ unsigned short lds[2][2][8192];  // 64 KB
  const int b = blockIdx.z, o0 = blockIdx.y * 128, s0 = blockIdx.x * 128;
  const int t = threadIdx.x, w = t >> 6, l = t & 63;
  const int wm = w >> 1, wn = w & 1, lr = l & 15;
  const int lkE = (l >> 4) * 8;
  const int swE = (lr & 7) * 8;
  const int cp = (t & 7) ^ ((t >> 3) & 7);

  const unsigned short* Ag = wqkv + (size_t)(o0 + (t >> 3)) * 512 + cp * 8;
  const unsigned short* Bg = xt + ((size_t)b * 4096 + s0 + (t >> 3)) * 512 + cp * 8;

  const f32x4 z = {0.f, 0.f, 0.f, 0.f};
  f32x4 acc[4][4];
  #pragma unroll
  for (int i = 0; i < 4; ++i)
    #pragma unroll
    for (int j = 0; j < 4; ++j) acc[i][j] = z;

#define STG_Q(st, kt) do { \
    _Pragma("unroll") \
    for (int j = 0; j < 4; ++j) { \
      GL16(Ag + (kt) * 64 + j * 32 * 512, (char*)&lds[st][0][0] + j * 4096 + t * 16); \
      GL16(Bg + (kt) * 64 + j * 32 * 512, (char*)&lds[st][1][0] + j * 4096 + t * 16); \
    } \
  } while (0)

#define CMP_Q(st) do { \
    const unsigned short* A  = &lds[st][0][0]; \
    const unsigned short* Bl = &lds[st][1][0]; \
    bf16x8 af[2][4], bfr[2][4]; \
    _Pragma("unroll") \
    for (int kc = 0; kc < 2; ++kc) { \
      const int kidx = (kc * 32 + lkE) ^ swE; \
      _Pragma("unroll") \
      for (int mi = 0; mi < 4; ++mi) af[kc][mi] = *(const bf16x8*)(A + (wm * 64 + mi * 16 + lr) * 64 + kidx); \
      _Pragma("unroll") \
      for (int ni = 0; ni < 4; ++ni) bfr[kc][ni] = *(const bf16x8*)(Bl + (wn * 64 + ni * 16 + lr) * 64 + kidx); \
    } \
    _Pragma("unroll") \
    for (int kc = 0; kc < 2; ++kc) \
      _Pragma("unroll") \
      for (int mi = 0; mi < 4; ++mi) \
        _Pragma("unroll") \
        for (int ni = 0; ni < 4; ++ni) \
          acc[mi][ni] = __builtin_amdgcn_mfma_f32_16x16x32_bf16(af[kc][mi], bfr[kc][ni], acc[mi][ni], 0, 0, 0); \
  } while (0)

  STG_Q(0, 0); STG_Q(1, 1);
  #pragma unroll
  for (int kt = 0; kt < 7; ++kt) {
    WAITVM(8);
    __builtin_amdgcn_s_barrier(); SCHEDBAR;
    CMP_Q(kt & 1);
    __builtin_amdgcn_s_barrier(); SCHEDBAR;
    if (kt + 2 < 8) STG_Q(kt & 1, kt + 2);
  }
  WAITVM(0);
  __builtin_amdgcn_s_barrier(); SCHEDBAR;
  CMP_Q(1);   // kt=7

  #pragma unroll
  for (int mi = 0; mi < 4; ++mi) {
    #pragma unroll
    for (int reg = 0; reg < 4; ++reg) {
      const int o = o0 + wm * 64 + mi * 16 + (l >> 4) * 4 + reg;
      const float bias = bqkv[o];
      const size_t base = (size_t)(o >> 8) * 16777216ull + ((size_t)b * 256 + (o & 255)) * 4096;
      #pragma unroll
      for (int ni = 0; ni < 4; ++ni) {
        const int s = s0 + wn * 64 + ni * 16 + lr;
        qkv[base + s] = f2b(acc[mi][ni][reg] + bias);
      }
    }
  }
#undef STG_Q
#undef CMP_Q
}

// ---------------- G2: per-group attention ----------------
__global__ __launch_bounds__(256) void k_attn(const unsigned short* __restrict__ qkv,
                                              unsigned short* __restrict__ yout)
{
  __shared__ unsigned short Vt[64][80];
  __shared__ unsigned short P[4][16][80];
  const int g = blockIdx.x;
  const unsigned short* qg = qkv + (size_t)g * 4096;
  const unsigned short* kg = qkv + 16777216ull + (size_t)g * 4096;
  const unsigned short* vg = qkv + 33554432ull + (size_t)g * 4096;
  const int t = threadIdx.x, w = t >> 6, l = t & 63;
  const int lr = l & 15, lk = (l >> 4) * 8;

  {
    const int j = t >> 2, c0 = (t & 3) * 16;
    bf16x8 a = *(const bf16x8*)(vg + j * 64 + c0);
    bf16x8 bb = *(const bf16x8*)(vg + j * 64 + c0 + 8);
    #pragma unroll
    for (int jj = 0; jj < 8; ++jj) { Vt[c0 + jj][j] = a[jj]; Vt[c0 + 8 + jj][j] = bb[jj]; }
  }

  const f32x4 z = {0.f, 0.f, 0.f, 0.f};
  bf16x8 qf[2];
  #pragma unroll
  for (int kc = 0; kc < 2; ++kc) qf[kc] = *(const bf16x8*)(qg + (w * 16 + lr) * 64 + kc * 32 + lk);
  f32x4 accS[4] = {z, z, z, z};
  __builtin_amdgcn_s_setprio(1);
  #pragma unroll
  for (int jt = 0; jt < 4; ++jt)
    #pragma unroll
    for (int kc = 0; kc < 2; ++kc) {
      bf16x8 kf = *(const bf16x8*)(kg + (jt * 16 + lr) * 64 + kc * 32 + lk);
      accS[jt] = __builtin_amdgcn_mfma_f32_16x16x32_bf16(qf[kc], kf, accS[jt], 0, 0, 0);
    }
  __builtin_amdgcn_s_setprio(0);

  #pragma unroll
  for (int reg = 0; reg < 4; ++reg) {
    float mx = fmaxf(fmaxf(accS[0][reg], accS[1][reg]), fmaxf(accS[2][reg], accS[3][reg]));
    #pragma unroll
    for (int m = 1; m < 16; m <<= 1) mx = fmaxf(mx, __shfl_xor(mx, m, 64));
    float e0 = __expf(accS[0][reg] - mx), e1 = __expf(accS[1][reg] - mx);
    float e2 = __expf(accS[2][reg] - mx), e3 = __expf(accS[3][reg] - mx);
    float sm = e0 + e1 + e2 + e3;
    #pragma unroll
    for (int m = 1; m < 16; m <<= 1) sm += __shfl_xor(sm, m, 64);
    const float rs = 1.f / sm;
    const int row = (l >> 4) * 4 + reg;
    P[w][row][0 * 16 + lr] = f2b(e0 * rs);
    P[w][row][1 * 16 + lr] = f2b(e1 * rs);
    P[w][row][2 * 16 + lr] = f2b(e2 * rs);
    P[w][row][3 * 16 + lr] = f2b(e3 * rs);
  }
  __syncthreads();

  bf16x8 pf[2];
  #pragma unroll
  for (int kc = 0; kc < 2; ++kc) pf[kc] = *(const bf16x8*)(&P[w][lr][kc * 32 + lk]);
  f32x4 accY[4] = {z, z, z, z};
  __builtin_amdgcn_s_setprio(1);
  #pragma unroll
  for (int nt = 0; nt < 4; ++nt)
    #pragma unroll
    for (int kc = 0; kc < 2; ++kc) {
      bf16x8 vf = *(const bf16x8*)(&Vt[nt * 16 + lr][kc * 32 + lk]);
      accY[nt] = __builtin_amdgcn_mfma_f32_16x16x32_bf16(pf[kc], vf, accY[nt], 0, 0, 0);
    }
  __builtin_amdgcn_s_setprio(0);

  unsigned short* yg = yout + (size_t)g * 4096;
  #pragma unroll
  for (int nt = 0; nt < 4; ++nt)
    #pragma unroll
    for (int reg = 0; reg < 4; ++reg) {
      const int i = w * 16 + (l >> 4) * 4 + reg;
      yg[i * 64 + nt * 16 + lr] = f2b(accY[nt][reg]);
    }
}

// ---------------- G3: recon GEMM + BN + residual; reads y via ds_read_b64_tr_b16 (round-12 proven) ----------------
__global__ __launch_bounds__(256) void k_recon(
    const unsigned short* __restrict__ y, const unsigned short* __restrict__ wrb,
    const float* __restrict__ scale, const float* __restrict__ off2,
    const float* __restrict__ x, float* __restrict__ out)
{
  __shared__ unsigned short Albuf[2][8192];   // A: [128 o][64 cr], XOR-swizzled
  __shared__ unsigned short Blbuf[2][8192];   // B: [16 cr4][8 sg][4][16]
  const int b = blockIdx.z, o0 = blockIdx.y * 128, s0 = blockIdx.x * 128;
  const int t = threadIdx.x, w = t >> 6, l = t & 63;
  const int wm = w >> 1, wn = w & 1, lr = l & 15, g = l >> 4;
  const int lkE = g * 8;
  const int swE = (lr & 7) * 8;
  const int cp = (t & 7) ^ ((t >> 3) & 7);

  const unsigned short* Ag = wrb + (size_t)(o0 + (t >> 3)) * 256 + cp * 8;
  const unsigned short* Bg = y + ((size_t)b * 256 + (t >> 2)) * 4096 + s0 + (t & 3) * 32;
  const int bwbase = (t >> 4) * 1024 + (t & 3) * 256 + ((t >> 2) & 3) * 32;
  const int trbase = g * 2048 + wn * 512 + lr * 8;

  const f32x4 z = {0.f, 0.f, 0.f, 0.f};
  f32x4 acc[4][4];
  #pragma unroll
  for (int i = 0; i < 4; ++i)
    #pragma unroll
    for (int j = 0; j < 4; ++j) acc[i][j] = z;

  uint4 br0, br1, br2, br3;

#define ASTG(st, kt) do { \
    _Pragma("unroll") \
    for (int j = 0; j < 4; ++j) \
      GL16(Ag + (kt) * 64 + j * 32 * 256, (char*)&Albuf[st][0] + j * 4096 + t * 16); \
  } while (0)

#define BLOAD(kt) do { \
    br0 = *(const uint4*)(Bg + (size_t)(kt) * 64 * 4096 + 0); \
    br1 = *(const uint4*)(Bg + (size_t)(kt) * 64 * 4096 + 8); \
    br2 = *(const uint4*)(Bg + (size_t)(kt) * 64 * 4096 + 16); \
    br3 = *(const uint4*)(Bg + (size_t)(kt) * 64 * 4096 + 24); \
  } while (0)

#define BWRITE(st) do { \
    char* bp_ = (char*)&Blbuf[st][0] + bwbase; \
    *(uint4*)(bp_ + 0)   = br0; \
    *(uint4*)(bp_ + 16)  = br1; \
    *(uint4*)(bp_ + 128) = br2; \
    *(uint4*)(bp_ + 144) = br3; \
  } while (0)

#define TR2(dst, k0, k1) do { \
    bf16x4 t0_, t1_; \
    asm volatile("ds_read_b64_tr_b16 %0, %1 offset:" #k0 : "=v"(t0_) : "v"(ta)); \
    asm volatile("ds_read_b64_tr_b16 %0, %1 offset:" #k1 : "=v"(t1_) : "v"(ta)); \
    (dst) = __builtin_shufflevector(t0_, t1_, 0, 1, 2, 3, 4, 5, 6, 7); \
  } while (0)

#define CMP_R(st) do { \
    const unsigned short* A = &Albuf[st][0]; \
    unsigned ta = LDSOFF(&Blbuf[st][0]) + (unsigned)trbase; \
    bf16x8 af[2][4], bfr[2][4]; \
    _Pragma("unroll") \
    for (int kc = 0; kc < 2; ++kc) { \
      const int kidx = (kc * 32 + lkE) ^ swE; \
      _Pragma("unroll") \
      for (int mi = 0; mi < 4; ++mi) af[kc][mi] = *(const bf16x8*)(A + (wm * 64 + mi * 16 + lr) * 64 + kidx); \
    } \
    TR2(bfr[0][0], 0, 1024);    TR2(bfr[0][1], 128, 1152); \
    TR2(bfr[0][2], 256, 1280);  TR2(bfr[0][3], 384, 1408); \
    TR2(bfr[1][0], 8192, 9216); TR2(bfr[1][1], 8320, 9344); \
    TR2(bfr[1][2], 8448, 9472); TR2(bfr[1][3], 8576, 9600); \
    WAITLGKM; SCHEDBAR; \
    _Pragma("unroll") \
    for (int kc = 0; kc < 2; ++kc) \
      _Pragma("unroll") \
      for (int mi = 0; mi < 4; ++mi) \
        _Pragma("unroll") \
        for (int ni = 0; ni < 4; ++ni) \
          acc[mi][ni] = __builtin_amdgcn_mfma_f32_16x16x32_bf16(af[kc][mi], bfr[kc][ni], acc[mi][ni], 0, 0, 0); \
  } while (0)

  // prologue
  ASTG(0, 0); BLOAD(0); ASTG(1, 1);
  WAITVM(4);
  BWRITE(0); BLOAD(1);
  WAITLGKM;
  __builtin_amdgcn_s_barrier(); SCHEDBAR;
  CMP_R(0);
  __builtin_amdgcn_s_barrier(); SCHEDBAR;
  ASTG(0, 2);
  WAITVM(4);
  BWRITE(1); BLOAD(2);
  WAITLGKM;
  __builtin_amdgcn_s_barrier(); SCHEDBAR;
  CMP_R(1);
  __builtin_amdgcn_s_barrier(); SCHEDBAR;
  ASTG(1, 3);
  WAITVM(4);
  BWRITE(0); BLOAD(3);
  WAITLGKM;
  __builtin_amdgcn_s_barrier(); SCHEDBAR;
  CMP_R(0);
  __builtin_amdgcn_s_barrier(); SCHEDBAR;
  WAITVM(0);
  BWRITE(1);
  WAITLGKM;
  __builtin_amdgcn_s_barrier(); SCHEDBAR;

  // ---- epilogue x prefetch: first two chunks issued BEFORE the last CMP so their
  // latency hides under the final 32 MFMAs ----
  const int lrow = (l >> 4) * 4;
  float xr0[16], xr1[16];

#define XLOAD(dstarr, mi) do { \
    _Pragma("unroll") \
    for (int reg = 0; reg < 4; ++reg) { \
      const int o_ = o0 + wm * 64 + (mi) * 16 + lrow + reg; \
      const size_t base_ = ((size_t)b * 512 + o_) * 4096; \
      _Pragma("unroll") \
      for (int ni = 0; ni < 4; ++ni) \
        dstarr[reg * 4 + ni] = x[base_ + s0 + wn * 64 + ni * 16 + lr]; \
    } \
  } while (0)

#define XSTORE(srcarr, mi) do { \
    _Pragma("unroll") \
    for (int reg = 0; reg < 4; ++reg) { \
      const int o_ = o0 + wm * 64 + (mi) * 16 + lrow + reg; \
      const float sc_ = scale[o_], of_ = off2[o_]; \
      const size_t base_ = ((size_t)b * 512 + o_) * 4096; \
      _Pragma("unroll") \
      for (int ni = 0; ni < 4; ++ni) { \
        const size_t idx_ = base_ + s0 + wn * 64 + ni * 16 + lr; \
        out[idx_] = acc[mi][ni][reg] * sc_ + of_ + srcarr[reg * 4 + ni]; \
      } \
    } \
  } while (0)

  XLOAD(xr0, 0);
  XLOAD(xr1, 1); SCHEDBAR;
  CMP_R(1);                     // kt=3 — x loads in flight during these MFMAs
  XSTORE(xr0, 0);
  XLOAD(xr0, 2); SCHEDBAR;
  XSTORE(xr1, 1);
  XLOAD(xr1, 3); SCHEDBAR;
  XSTORE(xr0, 2);
  XSTORE(xr1, 3);
#undef XLOAD
#undef XSTORE
#undef ASTG
#undef BLOAD
#undef BWRITE
#undef TR2
#undef CMP_R
}

extern "C" void kernel_launch(void* const* d_in, const int* in_sizes, int n_in,
                              void* d_out, int out_size, void* d_ws, size_t ws_size,
                              hipStream_t stream)
{
  const float* x     = (const float*)d_in[0];
  const float* Wq    = (const float*)d_in[1];
  const float* bq    = (const float*)d_in[2];
  const float* Wk    = (const float*)d_in[3];
  const float* bk    = (const float*)d_in[4];
  const float* Wv    = (const float*)d_in[5];
  const float* bv    = (const float*)d_in[6];
  const float* Wr    = (const float*)d_in[7];
  const float* br    = (const float*)d_in[8];
  const float* gamma = (const float*)d_in[9];
  const float* beta  = (const float*)d_in[10];
  const float* rm    = (const float*)d_in[11];
  const float* rv    = (const float*)d_in[12];

  char* ws = (char*)d_ws;
  unsigned short* wqkv  = (unsigned short*)(ws + OFF_WQKV);
  unsigned short* wrb   = (unsigned short*)(ws + OFF_WR);
  float* bqkv  = (float*)(ws + OFF_BQKV);
  float* scale = (float*)(ws + OFF_SCALE);
  float* off2  = (float*)(ws + OFF_OFF2);
  unsigned short* xt  = (unsigned short*)(ws + OFF_XT);
  unsigned short* yb  = (unsigned short*)(ws + OFF_Y);
  unsigned short* qkv = (unsigned short*)(ws + OFF_Q);
  float* out = (float*)d_out;

  hipLaunchKernelGGL(k_xt, dim3(64, 8, 16), dim3(256), 0, stream,
                     x, xt, Wq, bq, Wk, bk, Wv, bv, Wr, br, gamma, beta, rm, rv,
                     wqkv, wrb, bqkv, scale, off2);
  hipLaunchKernelGGL(k_qkv, dim3(32, 6, 16), dim3(256), 0, stream, xt, wqkv, bqkv, qkv);
  hipLaunchKernelGGL(k_attn, dim3(4096), dim3(256), 0, stream, qkv, yb);
  hipLaunchKernelGGL(k_recon, dim3(32, 4, 16), dim3(256), 0, stream, yb, wrb, scale, off2, x, out);
}